// Round 4
// baseline (347.715 us; speedup 1.0000x reference)
//
#include <hip/hip_runtime.h>
#include <hip/hip_bf16.h>

#define LRELU_ALPHA 0.3f
#define LN_EPS 1e-3f

typedef short bf16x8 __attribute__((ext_vector_type(8)));
typedef float f32x4 __attribute__((ext_vector_type(4)));

static __device__ __forceinline__ unsigned short f2bf(float f) {
    union { float f; unsigned u; } v; v.f = f;
    unsigned r = v.u + 0x7fffu + ((v.u >> 16) & 1u);  // RNE
    return (unsigned short)(r >> 16);
}

// ---------------------------------------------------------------------------
// Elementwise fp32 -> bf16 cast (n multiple of 4)
// ---------------------------------------------------------------------------
__global__ void cast_bf16(const float* __restrict__ X, unsigned short* __restrict__ Y, int n) {
    const int i = (blockIdx.x * 256 + threadIdx.x) * 4;
    if (i < n) {
        const float4 v = *(const float4*)(X + i);
        ushort4 o;
        o.x = f2bf(v.x); o.y = f2bf(v.y); o.z = f2bf(v.z); o.w = f2bf(v.w);
        *(ushort4*)(Y + i) = o;
    }
}

// ---------------------------------------------------------------------------
// W (K x N fp32, row-major) -> WT (N x Kp bf16, row-major), zero-pad k in [K,Kp)
// ---------------------------------------------------------------------------
__global__ void transpose_cast(const float* __restrict__ W, unsigned short* __restrict__ WT,
                               int K, int N, int Kp) {
    __shared__ float tile[32][33];
    const int tx = threadIdx.x, ty = threadIdx.y;
    const int kb = blockIdx.y * 32, nb = blockIdx.x * 32;
#pragma unroll
    for (int i = 0; i < 32; i += 8) {
        const int k = kb + ty + i;
        tile[ty + i][tx] = (k < K) ? W[(size_t)k * N + nb + tx] : 0.f;
    }
    __syncthreads();
#pragma unroll
    for (int i = 0; i < 32; i += 8) {
        const int n = nb + ty + i;
        const int k = kb + tx;
        WT[(size_t)n * Kp + k] = f2bf(tile[tx][ty + i]);
    }
}

// ---------------------------------------------------------------------------
// bf16 MFMA GEMM: C[M,N] fp32 = A[M,Kp]bf16 @ (BT[N,Kp]bf16)^T + bias
// Block tile 128x64, BK=32, 256 threads = 4 waves, wave tile 64x32 (4x2 mfma).
// ---------------------------------------------------------------------------
#define LDS_STRIDE 40
__global__ __launch_bounds__(256, 4)
void mfma_gemm(const unsigned short* __restrict__ A, int lda,
               const unsigned short* __restrict__ BT, int ldb,
               const float* __restrict__ bias, float* __restrict__ C,
               int M, int N, int K) {
    __shared__ unsigned short As[128 * LDS_STRIDE];
    __shared__ unsigned short Bs[64 * LDS_STRIDE];
    const int tid = threadIdx.x;
    const int w = tid >> 6, lane = tid & 63;
    const int q = lane >> 4, m16 = lane & 15;
    const int wr = (w >> 1) * 64, wc = (w & 1) * 32;
    const int br = blockIdx.y * 128, bc = blockIdx.x * 64;

    const int sr = (tid * 8) >> 5;   // 0..63
    const int sc = (tid * 8) & 31;   // 0,8,16,24

    f32x4 acc[4][2] = {};

    for (int k0 = 0; k0 < K; k0 += 32) {
        const uint4 va0 = *(const uint4*)(A + (size_t)(br + sr) * lda + k0 + sc);
        const uint4 va1 = *(const uint4*)(A + (size_t)(br + sr + 64) * lda + k0 + sc);
        const uint4 vb0 = *(const uint4*)(BT + (size_t)(bc + sr) * ldb + k0 + sc);
        *(uint4*)(As + sr * LDS_STRIDE + sc) = va0;
        *(uint4*)(As + (sr + 64) * LDS_STRIDE + sc) = va1;
        *(uint4*)(Bs + sr * LDS_STRIDE + sc) = vb0;
        __syncthreads();

        bf16x8 af[4], bfr[2];
#pragma unroll
        for (int i = 0; i < 4; ++i)
            af[i] = *(const bf16x8*)(As + (wr + 16 * i + m16) * LDS_STRIDE + q * 8);
#pragma unroll
        for (int j = 0; j < 2; ++j)
            bfr[j] = *(const bf16x8*)(Bs + (wc + 16 * j + m16) * LDS_STRIDE + q * 8);
#pragma unroll
        for (int i = 0; i < 4; ++i)
#pragma unroll
            for (int j = 0; j < 2; ++j)
                acc[i][j] = __builtin_amdgcn_mfma_f32_16x16x32_bf16(af[i], bfr[j], acc[i][j], 0, 0, 0);
        __syncthreads();
    }

#pragma unroll
    for (int i = 0; i < 4; ++i) {
        const int gr = br + wr + 16 * i + q * 4;
#pragma unroll
        for (int j = 0; j < 2; ++j) {
            const int gc = bc + wc + 16 * j + m16;
            const float b = bias[gc];
#pragma unroll
            for (int r = 0; r < 4; ++r)
                C[(size_t)(gr + r) * N + gc] = acc[i][j][r] + b;
        }
    }
}

// ---------------------------------------------------------------------------
// Skinny GEMM: t[M,15] = h[M,K] @ wb[K,15] + bb. One wave per row.
// ---------------------------------------------------------------------------
__global__ void small_gemm(const float* __restrict__ h, const float* __restrict__ wb,
                           const float* __restrict__ bb, float* __restrict__ t, int K) {
    const int w = threadIdx.x >> 6, lane = threadIdx.x & 63;
    const int row = blockIdx.x * 4 + w;
    float acc[15] = {};
    for (int k = lane; k < K; k += 64) {
        const float a = h[(size_t)row * K + k];
        const float* wr = wb + k * 15;
#pragma unroll
        for (int c = 0; c < 15; ++c) acc[c] += a * wr[c];
    }
#pragma unroll
    for (int c = 0; c < 15; ++c)
#pragma unroll
        for (int off = 32; off > 0; off >>= 1) acc[c] += __shfl_xor(acc[c], off, 64);
    if (lane < 15) t[row * 15 + lane] = acc[lane] + bb[lane];
}

// ---------------------------------------------------------------------------
// Batch diversity, LDS-tiled + j-split: t (N,15) -> dv_part (DIV_JC, N, 5)
// dv[i,k] = sum_j exp(-L1(ti_k - tj_k)); block (bx,jc) covers 16 i-rows x
// N/DIV_JC j-rows. 4 waves x 4 i-rows in registers; j staged in 256-row LDS
// tiles padded to 16 floats/row (4x ds_read_b128 per tj, <=2-way aliasing).
// Partials summed later by ln_lrelu (deterministic, no atomics).
// ---------------------------------------------------------------------------
#define DIV_TI 16
#define DIV_JC 4
__global__ __launch_bounds__(256, 4)
void diversity_kernel(const float* __restrict__ t, float* __restrict__ dv_part, int N) {
    const int tid = threadIdx.x;
    const int lane = tid & 63;
    const int g = tid >> 6;                    // wave id = i-group
    const int i0 = blockIdx.x * DIV_TI + g * 4;
    const int jc = blockIdx.y;
    const int jbeg = jc * (N / DIV_JC);
    const int jend = jbeg + N / DIV_JC;

    float ti[4][15];
#pragma unroll
    for (int r = 0; r < 4; ++r)
#pragma unroll
        for (int d = 0; d < 15; ++d)
            ti[r][d] = t[(i0 + r) * 15 + d];

    float acc[4][5] = {};

    __shared__ float tj_s[256 * 16];           // 16 KB, rows padded 15->16
    for (int j0 = jbeg; j0 < jend; j0 += 256) {
        __syncthreads();
#pragma unroll
        for (int it = 0; it < 15; ++it) {
            const int idx = it * 256 + tid;    // 0..3839, coalesced global read
            const int row = idx / 15;
            const int col = idx - row * 15;
            tj_s[row * 16 + col] = t[j0 * 15 + idx];
        }
        __syncthreads();
#pragma unroll
        for (int m = 0; m < 4; ++m) {
            const int jj = m * 64 + lane;
            float tj[16];
            *(float4*)(tj + 0)  = *(const float4*)(tj_s + jj * 16 + 0);
            *(float4*)(tj + 4)  = *(const float4*)(tj_s + jj * 16 + 4);
            *(float4*)(tj + 8)  = *(const float4*)(tj_s + jj * 16 + 8);
            *(float4*)(tj + 12) = *(const float4*)(tj_s + jj * 16 + 12);
#pragma unroll
            for (int r = 0; r < 4; ++r) {
#pragma unroll
                for (int k = 0; k < 5; ++k) {
                    const float s = fabsf(ti[r][3 * k]     - tj[3 * k])
                                  + fabsf(ti[r][3 * k + 1] - tj[3 * k + 1])
                                  + fabsf(ti[r][3 * k + 2] - tj[3 * k + 2]);
                    acc[r][k] += __expf(-s);
                }
            }
        }
    }

#pragma unroll
    for (int r = 0; r < 4; ++r)
#pragma unroll
        for (int k = 0; k < 5; ++k)
#pragma unroll
            for (int off = 32; off > 0; off >>= 1)
                acc[r][k] += __shfl_xor(acc[r][k], off, 64);

    if (lane == 0) {
        float* dst = dv_part + (size_t)jc * N * 5;
#pragma unroll
        for (int r = 0; r < 4; ++r)
#pragma unroll
            for (int k = 0; k < 5; ++k)
                dst[(i0 + r) * 5 + k] = acc[r][k];
    }
}

// ---------------------------------------------------------------------------
// concat([h, sum(dv_part)]) -> LayerNorm(center only) -> LeakyReLU.
// Writes fp32 out (M x 1029) and bf16 out (M x Cp), zero-padded cols [C,Cp).
// ---------------------------------------------------------------------------
__global__ void ln_lrelu(const float* __restrict__ h, const float* __restrict__ dv_part,
                         const float* __restrict__ beta, float* __restrict__ out,
                         unsigned short* __restrict__ out_bf,
                         int H, int D, int Cp, int M) {
    const int i = blockIdx.x;
    const int tid = threadIdx.x;
    const int C = H + D;
    float v[5];
    float s = 0.f, s2 = 0.f;
#pragma unroll
    for (int r = 0; r < 5; ++r) {
        const int c = tid + r * 256;
        if (c < C) {
            float x;
            if (c < H) {
                x = h[(size_t)i * H + c];
            } else {
                const int k = c - H;
                x = 0.f;
#pragma unroll
                for (int jc = 0; jc < DIV_JC; ++jc)
                    x += dv_part[(size_t)jc * M * D + i * D + k];
            }
            v[r] = x; s += x; s2 += x * x;
        }
    }
    __shared__ float rs[4], rs2[4];
    const int lane = tid & 63, wave = tid >> 6;
#pragma unroll
    for (int off = 32; off > 0; off >>= 1) {
        s += __shfl_down(s, off, 64);
        s2 += __shfl_down(s2, off, 64);
    }
    if (lane == 0) { rs[wave] = s; rs2[wave] = s2; }
    __syncthreads();
    const float S = rs[0] + rs[1] + rs[2] + rs[3];
    const float S2 = rs2[0] + rs2[1] + rs2[2] + rs2[3];
    const float mu = S / (float)C;
    const float var = S2 / (float)C - mu * mu;
    const float rstd = rsqrtf(var + LN_EPS);
#pragma unroll
    for (int r = 0; r < 5; ++r) {
        const int c = tid + r * 256;
        if (c < C) {
            float y = (v[r] - mu) * rstd + beta[c];
            y = (y >= 0.f) ? y : LRELU_ALPHA * y;
            out[(size_t)i * C + c] = y;
            out_bf[(size_t)i * Cp + c] = f2bf(y);
        } else if (c < Cp) {
            out_bf[(size_t)i * Cp + c] = 0;  // zero K-pad for next MFMA GEMM
        }
    }
}

// ---------------------------------------------------------------------------
// Critic head: out[i] = hc[i,:] . wf + bf  (C = 1029)
// ---------------------------------------------------------------------------
__global__ void head_kernel(const float* __restrict__ hc, const float* __restrict__ wf,
                            const float* __restrict__ bf, float* __restrict__ out, int C) {
    const int i = blockIdx.x;
    const int tid = threadIdx.x;
    float s = 0.f;
    for (int c = tid; c < C; c += 256) s += hc[(size_t)i * C + c] * wf[c];
    __shared__ float rs[4];
    const int lane = tid & 63, wave = tid >> 6;
#pragma unroll
    for (int off = 32; off > 0; off >>= 1) s += __shfl_down(s, off, 64);
    if (lane == 0) rs[wave] = s;
    __syncthreads();
    if (tid == 0) out[i] = rs[0] + rs[1] + rs[2] + rs[3] + bf[0];
}

extern "C" void kernel_launch(void* const* d_in, const int* in_sizes, int n_in,
                              void* d_out, int out_size, void* d_ws, size_t ws_size,
                              hipStream_t stream) {
    const float* x     = (const float*)d_in[0];
    const float* w0a   = (const float*)d_in[1];
    const float* b0a   = (const float*)d_in[2];
    const float* w0b   = (const float*)d_in[3];
    const float* b0b   = (const float*)d_in[4];
    const float* beta0 = (const float*)d_in[5];
    const float* w1a   = (const float*)d_in[6];
    const float* b1a   = (const float*)d_in[7];
    const float* w1b   = (const float*)d_in[8];
    const float* b1b   = (const float*)d_in[9];
    const float* beta1 = (const float*)d_in[10];
    const float* wf    = (const float*)d_in[11];
    const float* bf    = (const float*)d_in[12];
    float* out = (float*)d_out;

    const int M = 4096, NF = 512, HID = 1024, C = 1029, CP = 1056;

    // fp32 workspace
    float* h  = (float*)d_ws;                       // 4096 x 1024
    float* hc = h  + (size_t)M * HID;               // 4096 x 1029
    float* t  = hc + (size_t)M * C;                 // 4096 x 15
    float* dvp = t + (size_t)M * 15;                // DIV_JC x 4096 x 5
    // bf16 workspace
    unsigned short* x_bf  = (unsigned short*)(dvp + (size_t)DIV_JC * M * 5); // 4096 x 512
    unsigned short* hc_bf = x_bf  + (size_t)M * NF;                  // 4096 x 1056
    unsigned short* w0aT  = hc_bf + (size_t)M * CP;                  // 1024 x 512
    unsigned short* w1aT  = w0aT  + (size_t)HID * NF;                // 1024 x 1056

    cast_bf16<<<(M * NF) / 1024, 256, 0, stream>>>(x, x_bf, M * NF);
    transpose_cast<<<dim3(HID / 32, NF / 32), dim3(32, 8), 0, stream>>>(w0a, w0aT, NF, HID, NF);
    transpose_cast<<<dim3(HID / 32, CP / 32), dim3(32, 8), 0, stream>>>(w1a, w1aT, C, HID, CP);

    // ---- layer 0 ----
    mfma_gemm<<<dim3(HID / 64, M / 128), 256, 0, stream>>>(x_bf, NF, w0aT, NF, b0a, h, M, HID, NF);
    small_gemm<<<M / 4, 256, 0, stream>>>(h, w0b, b0b, t, HID);
    diversity_kernel<<<dim3(M / DIV_TI, DIV_JC), 256, 0, stream>>>(t, dvp, M);
    ln_lrelu<<<M, 256, 0, stream>>>(h, dvp, beta0, hc, hc_bf, HID, 5, CP, M);

    // ---- layer 1 ----
    mfma_gemm<<<dim3(HID / 64, M / 128), 256, 0, stream>>>(hc_bf, CP, w1aT, CP, b1a, h, M, HID, CP);
    small_gemm<<<M / 4, 256, 0, stream>>>(h, w1b, b1b, t, HID);
    diversity_kernel<<<dim3(M / DIV_TI, DIV_JC), 256, 0, stream>>>(t, dvp, M);
    ln_lrelu<<<M, 256, 0, stream>>>(h, dvp, beta1, hc, hc_bf, HID, 5, CP, M);

    // ---- head ----
    head_kernel<<<M, 256, 0, stream>>>(hc, wf, bf, out, C);
}

// Round 5
// 268.785 us; speedup vs baseline: 1.2937x; 1.2937x over previous
//
#include <hip/hip_runtime.h>
#include <hip/hip_bf16.h>

#define LRELU_ALPHA 0.3f
#define LN_EPS 1e-3f

typedef short bf16x8 __attribute__((ext_vector_type(8)));
typedef float f32x4 __attribute__((ext_vector_type(4)));

static __device__ __forceinline__ unsigned short f2bf(float f) {
    union { float f; unsigned u; } v; v.f = f;
    unsigned r = v.u + 0x7fffu + ((v.u >> 16) & 1u);  // RNE
    return (unsigned short)(r >> 16);
}

// ---------------------------------------------------------------------------
// Elementwise fp32 -> bf16 cast (n multiple of 4)
// ---------------------------------------------------------------------------
__global__ void cast_bf16(const float* __restrict__ X, unsigned short* __restrict__ Y, int n) {
    const int i = (blockIdx.x * 256 + threadIdx.x) * 4;
    if (i < n) {
        const float4 v = *(const float4*)(X + i);
        ushort4 o;
        o.x = f2bf(v.x); o.y = f2bf(v.y); o.z = f2bf(v.z); o.w = f2bf(v.w);
        *(ushort4*)(Y + i) = o;
    }
}

// ---------------------------------------------------------------------------
// W (K x N fp32, row-major) -> WT (N x Kp bf16, row-major), zero-pad k in [K,Kp)
// ---------------------------------------------------------------------------
__global__ void transpose_cast(const float* __restrict__ W, unsigned short* __restrict__ WT,
                               int K, int N, int Kp) {
    __shared__ float tile[32][33];
    const int tx = threadIdx.x, ty = threadIdx.y;
    const int kb = blockIdx.y * 32, nb = blockIdx.x * 32;
#pragma unroll
    for (int i = 0; i < 32; i += 8) {
        const int k = kb + ty + i;
        tile[ty + i][tx] = (k < K) ? W[(size_t)k * N + nb + tx] : 0.f;
    }
    __syncthreads();
#pragma unroll
    for (int i = 0; i < 32; i += 8) {
        const int n = nb + ty + i;
        const int k = kb + tx;
        WT[(size_t)n * Kp + k] = f2bf(tile[tx][ty + i]);
    }
}

// ---------------------------------------------------------------------------
// bf16 MFMA GEMM: C[M,N] fp32 = A[M,Kp]bf16 @ (BT[N,Kp]bf16)^T + bias
// Block tile 128x64, BK=32, 256 threads = 4 waves, wave tile 64x32 (4x2 mfma).
// ---------------------------------------------------------------------------
#define LDS_STRIDE 40
__global__ __launch_bounds__(256, 4)
void mfma_gemm(const unsigned short* __restrict__ A, int lda,
               const unsigned short* __restrict__ BT, int ldb,
               const float* __restrict__ bias, float* __restrict__ C,
               int M, int N, int K) {
    __shared__ unsigned short As[128 * LDS_STRIDE];
    __shared__ unsigned short Bs[64 * LDS_STRIDE];
    const int tid = threadIdx.x;
    const int w = tid >> 6, lane = tid & 63;
    const int q = lane >> 4, m16 = lane & 15;
    const int wr = (w >> 1) * 64, wc = (w & 1) * 32;
    const int br = blockIdx.y * 128, bc = blockIdx.x * 64;

    const int sr = (tid * 8) >> 5;   // 0..63
    const int sc = (tid * 8) & 31;   // 0,8,16,24

    f32x4 acc[4][2] = {};

    for (int k0 = 0; k0 < K; k0 += 32) {
        const uint4 va0 = *(const uint4*)(A + (size_t)(br + sr) * lda + k0 + sc);
        const uint4 va1 = *(const uint4*)(A + (size_t)(br + sr + 64) * lda + k0 + sc);
        const uint4 vb0 = *(const uint4*)(BT + (size_t)(bc + sr) * ldb + k0 + sc);
        *(uint4*)(As + sr * LDS_STRIDE + sc) = va0;
        *(uint4*)(As + (sr + 64) * LDS_STRIDE + sc) = va1;
        *(uint4*)(Bs + sr * LDS_STRIDE + sc) = vb0;
        __syncthreads();

        bf16x8 af[4], bfr[2];
#pragma unroll
        for (int i = 0; i < 4; ++i)
            af[i] = *(const bf16x8*)(As + (wr + 16 * i + m16) * LDS_STRIDE + q * 8);
#pragma unroll
        for (int j = 0; j < 2; ++j)
            bfr[j] = *(const bf16x8*)(Bs + (wc + 16 * j + m16) * LDS_STRIDE + q * 8);
#pragma unroll
        for (int i = 0; i < 4; ++i)
#pragma unroll
            for (int j = 0; j < 2; ++j)
                acc[i][j] = __builtin_amdgcn_mfma_f32_16x16x32_bf16(af[i], bfr[j], acc[i][j], 0, 0, 0);
        __syncthreads();
    }

#pragma unroll
    for (int i = 0; i < 4; ++i) {
        const int gr = br + wr + 16 * i + q * 4;
#pragma unroll
        for (int j = 0; j < 2; ++j) {
            const int gc = bc + wc + 16 * j + m16;
            const float b = bias[gc];
#pragma unroll
            for (int r = 0; r < 4; ++r)
                C[(size_t)(gr + r) * N + gc] = acc[i][j][r] + b;
        }
    }
}

// ---------------------------------------------------------------------------
// Skinny GEMM: t[M,15] = h[M,K] @ wb[K,15] + bb. One wave per row.
// ---------------------------------------------------------------------------
__global__ void small_gemm(const float* __restrict__ h, const float* __restrict__ wb,
                           const float* __restrict__ bb, float* __restrict__ t, int K) {
    const int w = threadIdx.x >> 6, lane = threadIdx.x & 63;
    const int row = blockIdx.x * 4 + w;
    float acc[15] = {};
    for (int k = lane; k < K; k += 64) {
        const float a = h[(size_t)row * K + k];
        const float* wr = wb + k * 15;
#pragma unroll
        for (int c = 0; c < 15; ++c) acc[c] += a * wr[c];
    }
#pragma unroll
    for (int c = 0; c < 15; ++c)
#pragma unroll
        for (int off = 32; off > 0; off >>= 1) acc[c] += __shfl_xor(acc[c], off, 64);
    if (lane < 15) t[row * 15 + lane] = acc[lane] + bb[lane];
}

// ---------------------------------------------------------------------------
// Batch diversity, LDS-tiled + j-split: t (N,15) -> dv_part (DIV_JC, N, 5)
// 4 waves x 4 i-rows in registers; j staged in 256-row LDS tiles (rows padded
// to 16 floats -> 4x ds_read_b128, <=2-way bank aliasing). All private arrays
// use unroll-constant indices only (SROA-safe: round-4's float4 pointer-cast
// writes into tj[] pinned it in scratch -> 230 MB HBM spill traffic).
// __launch_bounds__(256,2) lifts VGPR cap to 256 so ~120 live regs fit.
// ---------------------------------------------------------------------------
#define DIV_TI 16
#define DIV_JC 4
__global__ __launch_bounds__(256, 2)
void diversity_kernel(const float* __restrict__ t, float* __restrict__ dv_part, int N) {
    const int tid = threadIdx.x;
    const int lane = tid & 63;
    const int g = tid >> 6;                    // wave id = i-group
    const int i0 = blockIdx.x * DIV_TI + g * 4;
    const int jbeg = blockIdx.y * (N / DIV_JC);
    const int jend = jbeg + N / DIV_JC;

    float ti[4][15];
#pragma unroll
    for (int r = 0; r < 4; ++r)
#pragma unroll
        for (int d = 0; d < 15; ++d)
            ti[r][d] = t[(i0 + r) * 15 + d];

    float acc[4][5] = {};

    __shared__ float tj_s[256 * 16];           // 16 KB, rows padded 15->16
    for (int j0 = jbeg; j0 < jend; j0 += 256) {
        __syncthreads();
#pragma unroll
        for (int it = 0; it < 15; ++it) {
            const int idx = it * 256 + tid;    // coalesced global read
            const int row = idx / 15;
            const int col = idx - row * 15;
            tj_s[row * 16 + col] = t[j0 * 15 + idx];
        }
        __syncthreads();
#pragma unroll
        for (int m = 0; m < 4; ++m) {
            const float* rp = tj_s + (m * 64 + lane) * 16;
            const float4 tA = *(const float4*)(rp + 0);
            const float4 tB = *(const float4*)(rp + 4);
            const float4 tC = *(const float4*)(rp + 8);
            const float4 tD = *(const float4*)(rp + 12);
            float tj[15];
            tj[0] = tA.x;  tj[1] = tA.y;  tj[2] = tA.z;  tj[3] = tA.w;
            tj[4] = tB.x;  tj[5] = tB.y;  tj[6] = tB.z;  tj[7] = tB.w;
            tj[8] = tC.x;  tj[9] = tC.y;  tj[10] = tC.z; tj[11] = tC.w;
            tj[12] = tD.x; tj[13] = tD.y; tj[14] = tD.z;
#pragma unroll
            for (int r = 0; r < 4; ++r) {
#pragma unroll
                for (int k = 0; k < 5; ++k) {
                    const float s = fabsf(ti[r][3 * k]     - tj[3 * k])
                                  + fabsf(ti[r][3 * k + 1] - tj[3 * k + 1])
                                  + fabsf(ti[r][3 * k + 2] - tj[3 * k + 2]);
                    acc[r][k] += __expf(-s);
                }
            }
        }
    }

#pragma unroll
    for (int r = 0; r < 4; ++r)
#pragma unroll
        for (int k = 0; k < 5; ++k)
#pragma unroll
            for (int off = 32; off > 0; off >>= 1)
                acc[r][k] += __shfl_xor(acc[r][k], off, 64);

    if (lane == 0) {
        float* dst = dv_part + (size_t)blockIdx.y * N * 5;
#pragma unroll
        for (int r = 0; r < 4; ++r)
#pragma unroll
            for (int k = 0; k < 5; ++k)
                dst[(i0 + r) * 5 + k] = acc[r][k];
    }
}

// ---------------------------------------------------------------------------
// concat([h, sum(dv_part)]) -> LayerNorm(center only) -> LeakyReLU.
// Writes fp32 out (M x 1029) and bf16 out (M x Cp), zero-padded cols [C,Cp).
// ---------------------------------------------------------------------------
__global__ void ln_lrelu(const float* __restrict__ h, const float* __restrict__ dv_part,
                         const float* __restrict__ beta, float* __restrict__ out,
                         unsigned short* __restrict__ out_bf,
                         int H, int D, int Cp, int M) {
    const int i = blockIdx.x;
    const int tid = threadIdx.x;
    const int C = H + D;
    float v[5];
    float s = 0.f, s2 = 0.f;
#pragma unroll
    for (int r = 0; r < 5; ++r) {
        const int c = tid + r * 256;
        if (c < C) {
            float x;
            if (c < H) {
                x = h[(size_t)i * H + c];
            } else {
                const int k = c - H;
                x = 0.f;
#pragma unroll
                for (int jc = 0; jc < DIV_JC; ++jc)
                    x += dv_part[(size_t)jc * M * D + i * D + k];
            }
            v[r] = x; s += x; s2 += x * x;
        }
    }
    __shared__ float rs[4], rs2[4];
    const int lane = tid & 63, wave = tid >> 6;
#pragma unroll
    for (int off = 32; off > 0; off >>= 1) {
        s += __shfl_down(s, off, 64);
        s2 += __shfl_down(s2, off, 64);
    }
    if (lane == 0) { rs[wave] = s; rs2[wave] = s2; }
    __syncthreads();
    const float S = rs[0] + rs[1] + rs[2] + rs[3];
    const float S2 = rs2[0] + rs2[1] + rs2[2] + rs2[3];
    const float mu = S / (float)C;
    const float var = S2 / (float)C - mu * mu;
    const float rstd = rsqrtf(var + LN_EPS);
#pragma unroll
    for (int r = 0; r < 5; ++r) {
        const int c = tid + r * 256;
        if (c < C) {
            float y = (v[r] - mu) * rstd + beta[c];
            y = (y >= 0.f) ? y : LRELU_ALPHA * y;
            out[(size_t)i * C + c] = y;
            out_bf[(size_t)i * Cp + c] = f2bf(y);
        } else if (c < Cp) {
            out_bf[(size_t)i * Cp + c] = 0;  // zero K-pad for next MFMA GEMM
        }
    }
}

// ---------------------------------------------------------------------------
// Critic head: out[i] = hc[i,:] . wf + bf  (C = 1029)
// ---------------------------------------------------------------------------
__global__ void head_kernel(const float* __restrict__ hc, const float* __restrict__ wf,
                            const float* __restrict__ bf, float* __restrict__ out, int C) {
    const int i = blockIdx.x;
    const int tid = threadIdx.x;
    float s = 0.f;
    for (int c = tid; c < C; c += 256) s += hc[(size_t)i * C + c] * wf[c];
    __shared__ float rs[4];
    const int lane = tid & 63, wave = tid >> 6;
#pragma unroll
    for (int off = 32; off > 0; off >>= 1) s += __shfl_down(s, off, 64);
    if (lane == 0) rs[wave] = s;
    __syncthreads();
    if (tid == 0) out[i] = rs[0] + rs[1] + rs[2] + rs[3] + bf[0];
}

extern "C" void kernel_launch(void* const* d_in, const int* in_sizes, int n_in,
                              void* d_out, int out_size, void* d_ws, size_t ws_size,
                              hipStream_t stream) {
    const float* x     = (const float*)d_in[0];
    const float* w0a   = (const float*)d_in[1];
    const float* b0a   = (const float*)d_in[2];
    const float* w0b   = (const float*)d_in[3];
    const float* b0b   = (const float*)d_in[4];
    const float* beta0 = (const float*)d_in[5];
    const float* w1a   = (const float*)d_in[6];
    const float* b1a   = (const float*)d_in[7];
    const float* w1b   = (const float*)d_in[8];
    const float* b1b   = (const float*)d_in[9];
    const float* beta1 = (const float*)d_in[10];
    const float* wf    = (const float*)d_in[11];
    const float* bf    = (const float*)d_in[12];
    float* out = (float*)d_out;

    const int M = 4096, NF = 512, HID = 1024, C = 1029, CP = 1056;

    // fp32 workspace
    float* h  = (float*)d_ws;                       // 4096 x 1024
    float* hc = h  + (size_t)M * HID;               // 4096 x 1029
    float* t  = hc + (size_t)M * C;                 // 4096 x 15
    float* dvp = t + (size_t)M * 15;                // DIV_JC x 4096 x 5
    // bf16 workspace
    unsigned short* x_bf  = (unsigned short*)(dvp + (size_t)DIV_JC * M * 5); // 4096 x 512
    unsigned short* hc_bf = x_bf  + (size_t)M * NF;                  // 4096 x 1056
    unsigned short* w0aT  = hc_bf + (size_t)M * CP;                  // 1024 x 512
    unsigned short* w1aT  = w0aT  + (size_t)HID * NF;                // 1024 x 1056

    cast_bf16<<<(M * NF) / 1024, 256, 0, stream>>>(x, x_bf, M * NF);
    transpose_cast<<<dim3(HID / 32, NF / 32), dim3(32, 8), 0, stream>>>(w0a, w0aT, NF, HID, NF);
    transpose_cast<<<dim3(HID / 32, CP / 32), dim3(32, 8), 0, stream>>>(w1a, w1aT, C, HID, CP);

    // ---- layer 0 ----
    mfma_gemm<<<dim3(HID / 64, M / 128), 256, 0, stream>>>(x_bf, NF, w0aT, NF, b0a, h, M, HID, NF);
    small_gemm<<<M / 4, 256, 0, stream>>>(h, w0b, b0b, t, HID);
    diversity_kernel<<<dim3(M / DIV_TI, DIV_JC), 256, 0, stream>>>(t, dvp, M);
    ln_lrelu<<<M, 256, 0, stream>>>(h, dvp, beta0, hc, hc_bf, HID, 5, CP, M);

    // ---- layer 1 ----
    mfma_gemm<<<dim3(HID / 64, M / 128), 256, 0, stream>>>(hc_bf, CP, w1aT, CP, b1a, h, M, HID, CP);
    small_gemm<<<M / 4, 256, 0, stream>>>(h, w1b, b1b, t, HID);
    diversity_kernel<<<dim3(M / DIV_TI, DIV_JC), 256, 0, stream>>>(t, dvp, M);
    ln_lrelu<<<M, 256, 0, stream>>>(h, dvp, beta1, hc, hc_bf, HID, 5, CP, M);

    // ---- head ----
    head_kernel<<<M, 256, 0, stream>>>(hc, wf, bf, out, C);
}